// Round 2
// baseline (367.757 us; speedup 1.0000x reference)
//
#include <hip/hip_runtime.h>

// Problem constants (from reference setup_inputs): N=32, HW=4096, A=5, C=80
#define NBOX (32 * 4096 * 5)   // 655360 boxes
#define HWA  (4096 * 5)        // 20480 (prior repeats across N)
#define THRESHOLD 0.5f

// MEASUREMENT ROUND: kernel body is identical to the 299.7us baseline.
// kernel_launch issues it 3x (idempotent: same inputs -> same outputs), so
// dur_us_new - dur_us_old = 2 * T_kernel. This disambiguates how much of the
// ~300us headline is harness poison-fill (800 MiB fills @ ~123us seen in
// rocprof) vs. our kernel, which never appears in the top-5 dispatch table.
__global__ __launch_bounds__(256) void detector_kernel(
    const float4* __restrict__ box,     // NBOX float4 (cx,cy,w,h)
    const float*  __restrict__ conf,    // NBOX
    const float4* __restrict__ cls4,    // NBOX * 20 float4 (80 classes)
    const float4* __restrict__ prior,   // HWA float4
    const unsigned int* __restrict__ fs_word,
    float4* __restrict__ box_out,       // NBOX float4
    float*  __restrict__ probs_out,     // NBOX
    float*  __restrict__ idx_out)       // NBOX (class index stored as float)
{
    const int t       = threadIdx.x;
    const int lane    = t & 63;
    const int waveIdx = blockIdx.x * 4 + (t >> 6);
    const int boxBase = waveIdx * 16;          // 16 boxes per wave
    const int slot    = lane & 3;              // which float4 column group
    const int myBox   = boxBase + (lane >> 2); // scoring box for this lane

    // ---- issue decode loads early (redundant across quads; same cache lines) ----
    const int obox = boxBase + (lane & 15);    // output box for lanes 0..15
    const float4 b = box[obox];
    const float4 p = prior[obox % HWA];
    const unsigned int w = *fs_word;

    // conf of my scoring box (4 lanes share an address -> broadcast)
    const float cf = conf[myBox];

    // ---- class scores: 5 independent float4 loads per lane ----
    const float4* row = cls4 + (size_t)myBox * 20 + slot;
    const float4 v0 = row[0];
    const float4 v1 = row[4];
    const float4 v2 = row[8];
    const float4 v3 = row[12];
    const float4 v4 = row[16];

    // ---- per-lane argmax (indices ascend -> strict '>' = np.argmax first-wins) ----
    float m  = -1.0f;   // all products >= 0
    int   mi = 0;
    const int c0 = slot * 4;
#define STEP(V, K) { \
        const float s0 = cf * (V).x, s1 = cf * (V).y, s2 = cf * (V).z, s3 = cf * (V).w; \
        const int c = c0 + 16 * (K); \
        if (s0 > m) { m = s0; mi = c;     } \
        if (s1 > m) { m = s1; mi = c + 1; } \
        if (s2 > m) { m = s2; mi = c + 2; } \
        if (s3 > m) { m = s3; mi = c + 3; } }
    STEP(v0, 0) STEP(v1, 1) STEP(v2, 2) STEP(v3, 3) STEP(v4, 4)
#undef STEP

    // ---- quad butterfly reduce: pack (score_bits<<32)|(127-idx); scores>=0 so
    //      float bits are monotone; ties -> larger low word = smaller class idx ----
    unsigned long long packed =
        ((unsigned long long)__float_as_uint(m) << 32) | (unsigned int)(127 - mi);
    unsigned long long o;
    o = __shfl_xor(packed, 1, 64); if (o > packed) packed = o;
    o = __shfl_xor(packed, 2, 64); if (o > packed) packed = o;

    // gather quad q's result (lane 4q) into lane q for compact output
    const unsigned long long res = __shfl(packed, (lane & 15) * 4, 64);

    // ---- decode + output (lanes 0..15 of each wave) ----
    const float fs  = (w < 1000000u) ? (float)w : __uint_as_float(w);
    const float inv = 1.0f / fs;               // fs = 64 -> exact
    const float cx = b.x + p.x;
    const float cy = b.y + p.y;
    const float hx = (b.z * p.z) * 0.5f;
    const float hy = (b.w * p.w) * 0.5f;

    const float mm   = __uint_as_float((unsigned int)(res >> 32));
    const int   midx = 127 - (int)(res & 0x7Fu);
    const bool  keep = (mm > THRESHOLD);

    if (lane < 16) {
        float4 bo;
        bo.x = keep ? (cx - hx) * inv : 0.0f;
        bo.y = keep ? (cy - hy) * inv : 0.0f;
        bo.z = keep ? (cx + hx) * inv : 0.0f;
        bo.w = keep ? (cy + hy) * inv : 0.0f;
        box_out[obox]   = bo;
        probs_out[obox] = keep ? mm : 0.0f;
        idx_out[obox]   = (float)midx;
    }
}

extern "C" void kernel_launch(void* const* d_in, const int* in_sizes, int n_in,
                              void* d_out, int out_size, void* d_ws, size_t ws_size,
                              hipStream_t stream) {
    const float4* box   = (const float4*)d_in[0];
    const float*  conf  = (const float*)d_in[1];
    const float4* cls4  = (const float4*)d_in[2];
    const float4* prior = (const float4*)d_in[3];
    const unsigned int* fs = (const unsigned int*)d_in[4];

    float* out = (float*)d_out;
    float4* box_out  = (float4*)out;                 // NBOX float4 = 4*NBOX floats
    float* probs_out = out + (size_t)4 * NBOX;       // NBOX floats
    float* idx_out   = probs_out + NBOX;             // NBOX floats

    // 256 threads = 4 waves = 64 boxes per block
    const int blocks = NBOX / 64;                    // 10240

    // Launch 3x (idempotent). Extra 2 launches exist purely to measure
    // T_kernel = (dur_us - baseline) / 2 from the harness timing.
    for (int rep = 0; rep < 3; ++rep) {
        detector_kernel<<<blocks, 256, 0, stream>>>(
            box, conf, cls4, prior, fs, box_out, probs_out, idx_out);
    }
}

// Round 3
// 299.650 us; speedup vs baseline: 1.2273x; 1.2273x over previous
//
#include <hip/hip_runtime.h>

// Problem constants (from reference setup_inputs): N=32, HW=4096, A=5, C=80
#define NBOX (32 * 4096 * 5)   // 655360 boxes
#define HWA  (4096 * 5)        // 20480 (prior repeats across N)
#define THRESHOLD 0.5f

// One wave = 16 boxes, 4 lanes per box, 5 float4 per lane.
// For quad q at iteration k, lanes read box q's bytes [64k,64k+64) -> one full
// 64B line per quad per instruction == perfect-coalescing line count. No LDS.
//
// Measured (r2, 3x-launch delta): T_kernel ~= 34 us vs 37.8 us analytic HBM
// floor (238 MB mandatory traffic @ 6.3 TB/s) -> at the memory roofline.
// Headline ~300 us is dominated by two 800-MiB harness poison fills (~123 us
// each, seen in rocprof) inside the timed region — outside kernel control.
__global__ __launch_bounds__(256) void detector_kernel(
    const float4* __restrict__ box,     // NBOX float4 (cx,cy,w,h)
    const float*  __restrict__ conf,    // NBOX
    const float4* __restrict__ cls4,    // NBOX * 20 float4 (80 classes)
    const float4* __restrict__ prior,   // HWA float4
    const unsigned int* __restrict__ fs_word,
    float4* __restrict__ box_out,       // NBOX float4
    float*  __restrict__ probs_out,     // NBOX
    float*  __restrict__ idx_out)       // NBOX (class index stored as float)
{
    const int t       = threadIdx.x;
    const int lane    = t & 63;
    const int waveIdx = blockIdx.x * 4 + (t >> 6);
    const int boxBase = waveIdx * 16;          // 16 boxes per wave
    const int slot    = lane & 3;              // which float4 column group
    const int myBox   = boxBase + (lane >> 2); // scoring box for this lane

    // ---- issue decode loads early (redundant across quads; same cache lines) ----
    const int obox = boxBase + (lane & 15);    // output box for lanes 0..15
    const float4 b = box[obox];
    const float4 p = prior[obox % HWA];
    const unsigned int w = *fs_word;

    // conf of my scoring box (4 lanes share an address -> broadcast)
    const float cf = conf[myBox];

    // ---- class scores: 5 independent float4 loads per lane ----
    const float4* row = cls4 + (size_t)myBox * 20 + slot;
    const float4 v0 = row[0];
    const float4 v1 = row[4];
    const float4 v2 = row[8];
    const float4 v3 = row[12];
    const float4 v4 = row[16];

    // ---- per-lane argmax (indices ascend -> strict '>' = np.argmax first-wins) ----
    float m  = -1.0f;   // all products >= 0
    int   mi = 0;
    const int c0 = slot * 4;
#define STEP(V, K) { \
        const float s0 = cf * (V).x, s1 = cf * (V).y, s2 = cf * (V).z, s3 = cf * (V).w; \
        const int c = c0 + 16 * (K); \
        if (s0 > m) { m = s0; mi = c;     } \
        if (s1 > m) { m = s1; mi = c + 1; } \
        if (s2 > m) { m = s2; mi = c + 2; } \
        if (s3 > m) { m = s3; mi = c + 3; } }
    STEP(v0, 0) STEP(v1, 1) STEP(v2, 2) STEP(v3, 3) STEP(v4, 4)
#undef STEP

    // ---- quad butterfly reduce: pack (score_bits<<32)|(127-idx); scores>=0 so
    //      float bits are monotone; ties -> larger low word = smaller class idx ----
    unsigned long long packed =
        ((unsigned long long)__float_as_uint(m) << 32) | (unsigned int)(127 - mi);
    unsigned long long o;
    o = __shfl_xor(packed, 1, 64); if (o > packed) packed = o;
    o = __shfl_xor(packed, 2, 64); if (o > packed) packed = o;

    // gather quad q's result (lane 4q) into lane q for compact output
    const unsigned long long res = __shfl(packed, (lane & 15) * 4, 64);

    // ---- decode + output (lanes 0..15 of each wave) ----
    const float fs  = (w < 1000000u) ? (float)w : __uint_as_float(w);
    const float inv = 1.0f / fs;               // fs = 64 -> exact
    const float cx = b.x + p.x;
    const float cy = b.y + p.y;
    const float hx = (b.z * p.z) * 0.5f;
    const float hy = (b.w * p.w) * 0.5f;

    const float mm   = __uint_as_float((unsigned int)(res >> 32));
    const int   midx = 127 - (int)(res & 0x7Fu);
    const bool  keep = (mm > THRESHOLD);

    if (lane < 16) {
        float4 bo;
        bo.x = keep ? (cx - hx) * inv : 0.0f;
        bo.y = keep ? (cy - hy) * inv : 0.0f;
        bo.z = keep ? (cx + hx) * inv : 0.0f;
        bo.w = keep ? (cy + hy) * inv : 0.0f;
        box_out[obox]   = bo;
        probs_out[obox] = keep ? mm : 0.0f;
        idx_out[obox]   = (float)midx;
    }
}

extern "C" void kernel_launch(void* const* d_in, const int* in_sizes, int n_in,
                              void* d_out, int out_size, void* d_ws, size_t ws_size,
                              hipStream_t stream) {
    const float4* box   = (const float4*)d_in[0];
    const float*  conf  = (const float*)d_in[1];
    const float4* cls4  = (const float4*)d_in[2];
    const float4* prior = (const float4*)d_in[3];
    const unsigned int* fs = (const unsigned int*)d_in[4];

    float* out = (float*)d_out;
    float4* box_out  = (float4*)out;                 // NBOX float4 = 4*NBOX floats
    float* probs_out = out + (size_t)4 * NBOX;       // NBOX floats
    float* idx_out   = probs_out + NBOX;             // NBOX floats

    // 256 threads = 4 waves = 64 boxes per block
    const int blocks = NBOX / 64;                    // 10240
    detector_kernel<<<blocks, 256, 0, stream>>>(
        box, conf, cls4, prior, fs, box_out, probs_out, idx_out);
}